// Round 3
// baseline (11802.624 us; speedup 1.0000x reference)
//
#include <hip/hip_runtime.h>
#include <stdint.h>

typedef unsigned short u16;
typedef unsigned int   u32;

typedef short bf16x8 __attribute__((ext_vector_type(8)));   // 8 bf16 in 4 VGPRs
typedef float f32x4  __attribute__((ext_vector_type(4)));

#define NROWS  2048
#define HID    256
#define BATCH  8
#define NSTEPS 10
#define MTILE  16            // rows per workgroup
#define NWGS   (NROWS/MTILE) // 128
#define THREADS 256          // 4 waves, 1 wave/SIMD -> 512-reg budget

// ---------- helpers ----------
__device__ __forceinline__ u16 f2bf(float f) {
    union { float f; u32 u; } v; v.f = f;
    u32 r = (v.u + 0x7FFFu + ((v.u >> 16) & 1u)) >> 16;   // RNE
    return (u16)r;
}
__device__ __forceinline__ float sigm(float x) {
    return 1.0f / (1.0f + __expf(-x));
}
__device__ __forceinline__ float ftanh(float x) {
    x = fminf(fmaxf(x, -15.0f), 15.0f);
    float a = __expf(2.0f * x);
    return (a - 1.0f) / (a + 1.0f);
}
__device__ __forceinline__ f32x4 mfma16(bf16x8 a, bf16x8 b, f32x4 c) {
    return __builtin_amdgcn_mfma_f32_16x16x32_bf16(a, b, c, 0, 0, 0);
}
// packed weight B-fragment load: contiguous 16B per lane, 1KB per wave-load
__device__ __forceinline__ bf16x8 loadB(const u16* __restrict__ base, int ct, int kt, int ln) {
    return ((const bf16x8*)base)[(ct * 8 + kt) * 64 + ln];
}
// barrier that does NOT drain vmcnt: LDS visibility via lgkmcnt(0) only.
__device__ __forceinline__ void barrier_lgkm() {
    asm volatile("s_waitcnt lgkmcnt(0)" ::: "memory");
    __builtin_amdgcn_s_barrier();
    asm volatile("" ::: "memory");
}

// ---------- setup kernels (unchanged, validated) ----------
__global__ __launch_bounds__(256) void stode_wz(const float* __restrict__ Wf,
                                                const float* __restrict__ Ws2,
                                                float* __restrict__ Wz) {
    int a = blockIdx.x;
    int b = threadIdx.x;
    const float* wf2 = Wf + a * 512 + 256;
    float acc = 0.0f;
    for (int c = 0; c < 256; ++c) acc += wf2[c] * Ws2[c * 256 + b];
    Wz[a * 256 + b] = acc;
}
__global__ __launch_bounds__(256) void stode_biasf(const float* __restrict__ Wf,
                                                   const float* __restrict__ Ws2b,
                                                   const float* __restrict__ Wfb,
                                                   float* __restrict__ biasf) {
    int a = threadIdx.x;
    const float* wf2 = Wf + a * 512 + 256;
    float acc = Wfb[a];
    for (int c = 0; c < 256; ++c) acc += wf2[c] * Ws2b[c];
    biasf[a] = acc;
}
__global__ __launch_bounds__(256) void stode_pack(const float* __restrict__ Wg,
                                                  const float* __restrict__ Ws1,
                                                  const float* __restrict__ Wc,
                                                  const float* __restrict__ Wz,
                                                  const float* __restrict__ Wf,
                                                  u16* __restrict__ P1,
                                                  u16* __restrict__ P2,
                                                  u16* __restrict__ P3) {
    int i = blockIdx.x * 256 + threadIdx.x;
    const int NP1 = 48 * 8 * 64 * 8;
    const int NP2 = 32 * 8 * 64 * 8;
    int region, local;
    if (i < NP1)            { region = 0; local = i; }
    else if (i < NP1 + NP2) { region = 1; local = i - NP1; }
    else                    { region = 2; local = i - NP1 - NP2; }
    int j    = local & 7;
    int lane = (local >> 3) & 63;
    int kt   = (local >> 9) & 7;
    int ct   = local >> 12;
    int k = kt * 32 + (lane >> 4) * 8 + j;
    int c = lane & 15;
    if (region == 0) {
        float v = (ct < 32) ? Wg[(16 * ct + c) * 256 + k]
                            : Ws1[(16 * (ct - 32) + c) * 256 + k];
        P1[local] = f2bf(v);
    } else if (region == 1) {
        float v = (ct < 16) ? Wc[(16 * ct + c) * 256 + k]
                            : Wz[(16 * (ct - 16) + c) * 256 + k];
        P2[local] = f2bf(v);
    } else {
        float v = Wf[(16 * ct + c) * 512 + k];
        P3[local] = f2bf(v);
    }
}

// ---------- main persistent integrator ----------
// LDS (bytes): X1/X3 alias @0 (8K), X2a @8192 (8K), X2b @16384 (8K), R @24576 (128K) = 155648
#define X1B   0
#define X2aB  8192
#define X2bB  16384
#define WLB   24576

__global__ __launch_bounds__(THREADS, 1) void stode_main(
    const float* __restrict__ h0, const float* __restrict__ tspans,
    const float* __restrict__ Wg_b, const float* __restrict__ Wc_b,
    const float* __restrict__ Wt,   const float* __restrict__ Ws1_b,
    const u16* __restrict__ P1p, const u16* __restrict__ P2p, const u16* __restrict__ P3p,
    const float* __restrict__ biasf, float* __restrict__ out)
{
    __shared__ u16 SH[77824];   // 155648 bytes
    char* shb = (char*)SH;

    const int tid = threadIdx.x;
    const int wv  = tid >> 6;    // 0..3
    const int ln  = tid & 63;
    const int lr  = ln & 15;
    const int lg  = ln >> 4;
    const int wg  = blockIdx.x;
    const float third = 1.0f / 3.0f;

    // A-frag read bases: addr(k) = (k even ? tbE : tbO) + xb + k*64 (reproduces XOR swizzle)
    const int base0 = lr * 512 + ((lg * 16) ^ ((lr & 3) << 4));
    const int flp   = (lr & 4) ? 64 : 0;
    const int tbE   = base0 + flp;
    const int tbO   = base0 - flp;
    const int rBase = WLB + (wv << 15) + (ln << 4);   // LDS-resident R base

    auto ldAF = [&](bf16x8 (&af)[4], int xb, int ktH) {
        #pragma unroll
        for (int kk = 0; kk < 4; ++kk) {
            int k = 4 * ktH + kk;
            af[kk] = *(const bf16x8*)(shb + ((k & 1) ? tbO : tbE) + xb + k * 64);
        }
    };
    auto st16 = [&](int xb, int row, int col, u16 v) {
        int byte = (xb + row * 512 + col * 2) ^ ((row & 7) << 4);
        *(u16*)(shb + byte) = v;
    };
    auto issue2 = [&](bf16x8 (&buf)[2][4], const u16* __restrict__ P, int ctbase, int th, int ktH) {
        #pragma unroll
        for (int i = 0; i < 2; ++i)
            #pragma unroll
            for (int kk = 0; kk < 4; ++kk)
                buf[i][kk] = loadB(P, ctbase + 2 * th + i, 4 * ktH + kk, ln);
    };
    auto mm2 = [&](f32x4 (&acc)[4], const bf16x8 (&af)[4], const bf16x8 (&buf)[2][4], int th) {
        #pragma unroll
        for (int i = 0; i < 2; ++i)
            #pragma unroll
            for (int kk = 0; kk < 4; ++kk)
                acc[2 * th + i] = mfma16(af[kk], buf[i][kk], acc[2 * th + i]);
    };

    // ---- one-time residency ----
    bf16x8 zf[4][8], sf[4][8];        // 256 persistent regs of weights
    #pragma unroll
    for (int t = 0; t < 4; ++t)
        #pragma unroll
        for (int kt = 0; kt < 8; ++kt) {
            zf[t][kt] = loadB(P1p,      4 * wv + t, kt, ln);
            sf[t][kt] = loadB(P1p, 32 + 4 * wv + t, kt, ln);
        }
    #pragma unroll
    for (int t = 0; t < 4; ++t)
        #pragma unroll
        for (int kt = 0; kt < 8; ++kt) {
            bf16x8 f = loadB(P1p, 16 + 4 * wv + t, kt, ln);
            *(bf16x8*)(shb + rBase + ((t * 8 + kt) << 10)) = f;
        }

    // biases / Wt : col = 64*wv + 16*t + lr
    float bz[4], br[4], bs1[4], bc[4], bfv[4], wtv[4];
    #pragma unroll
    for (int t = 0; t < 4; ++t) {
        int c = 64 * wv + 16 * t + lr;
        bz[t]  = Wg_b[c];
        br[t]  = Wg_b[256 + c];
        bs1[t] = Ws1_b[c];
        bc[t]  = Wc_b[c];
        bfv[t] = biasf[c];
        wtv[t] = Wt[c];
    }

    // state at C/D positions: row = 4*lg + r, col = 64*wv + 16*t + lr
    float y[4][4], kA[4][4], kB[4][4], zreg[4][4];
    #pragma unroll
    for (int t = 0; t < 4; ++t)
        #pragma unroll
        for (int r = 0; r < 4; ++r) {
            int row = wg * MTILE + 4 * lg + r;
            int col = 64 * wv + 16 * t + lr;
            y[t][r] = h0[row * 256 + col];
        }

    __syncthreads();   // residency visible (full drain, once)

    float dt = 0.0f;   // set per interval

    // E recomputation (bit-identical to reference expressions per RK stage)
    auto calcE = [&](float (&Ev)[4][4], int RK) {
        if (RK == 1) {
            #pragma unroll
            for (int t = 0; t < 4; ++t)
                #pragma unroll
                for (int r = 0; r < 4; ++r) Ev[t][r] = y[t][r];
        } else if (RK == 2) {
            float c = dt * third;
            #pragma unroll
            for (int t = 0; t < 4; ++t)
                #pragma unroll
                for (int r = 0; r < 4; ++r) Ev[t][r] = y[t][r] + c * kA[t][r];
        } else if (RK == 3) {
            #pragma unroll
            for (int t = 0; t < 4; ++t)
                #pragma unroll
                for (int r = 0; r < 4; ++r) Ev[t][r] = y[t][r] + dt * (kB[t][r] - third * kA[t][r]);
        } else {
            #pragma unroll
            for (int t = 0; t < 4; ++t)
                #pragma unroll
                for (int r = 0; r < 4; ++r) Ev[t][r] = y[t][r] + dt * kB[t][r];
        }
    };

    auto EVAL = [&](float te, int RK) {
        bf16x8 bufA[2][4], bufB[2][4];
        issue2(bufA, P2p, 4 * wv, 0, 0);   // C chunk (th0,ktH0)
        issue2(bufB, P2p, 4 * wv, 0, 1);   // C chunk (th0,ktH1)

        // stage X1 = bf16(E)
        {
            float Ev[4][4]; calcE(Ev, RK);
            #pragma unroll
            for (int t = 0; t < 4; ++t)
                #pragma unroll
                for (int r = 0; r < 4; ++r)
                    st16(X1B, 4 * lg + r, 64 * wv + 16 * t + lr, f2bf(Ev[t][r]));
        }
        barrier_lgkm();   // B1

        // ---- P1: Z (reg), R (lds), S (reg) ----
        f32x4 aZ[4], aR[4], aS[4];
        #pragma unroll
        for (int t = 0; t < 4; ++t) {
            aZ[t] = f32x4{0.f, 0.f, 0.f, 0.f};
            aR[t] = f32x4{0.f, 0.f, 0.f, 0.f};
            aS[t] = f32x4{0.f, 0.f, 0.f, 0.f};
        }
        bf16x8 af[4];
        #pragma unroll
        for (int ktH = 0; ktH < 2; ++ktH) {
            ldAF(af, X1B, ktH);
            #pragma unroll
            for (int t = 0; t < 4; ++t)
                #pragma unroll
                for (int kk = 0; kk < 4; ++kk)
                    aZ[t] = mfma16(af[kk], zf[t][4 * ktH + kk], aZ[t]);
            #pragma unroll
            for (int t = 0; t < 4; ++t) {
                #pragma unroll
                for (int kp = 0; kp < 2; ++kp) {
                    bf16x8 rf0 = *(const bf16x8*)(shb + rBase + ((t * 8 + 4 * ktH + 2 * kp) << 10));
                    bf16x8 rf1 = *(const bf16x8*)(shb + rBase + ((t * 8 + 4 * ktH + 2 * kp + 1) << 10));
                    aR[t] = mfma16(af[2 * kp],     rf0, aR[t]);
                    aR[t] = mfma16(af[2 * kp + 1], rf1, aR[t]);
                }
            }
            #pragma unroll
            for (int t = 0; t < 4; ++t)
                #pragma unroll
                for (int kk = 0; kk < 4; ++kk)
                    aS[t] = mfma16(af[kk], sf[t][4 * ktH + kk], aS[t]);
        }

        // epilogue-1
        {
            float Ev[4][4]; calcE(Ev, RK);
            #pragma unroll
            for (int t = 0; t < 4; ++t)
                #pragma unroll
                for (int r = 0; r < 4; ++r) {
                    zreg[t][r] = sigm(aZ[t][r] + bz[t]);
                    float rr   = sigm(aR[t][r] + br[t]);
                    float s    = ftanh(aS[t][r] + bs1[t]);
                    int row = 4 * lg + r, col = 64 * wv + 16 * t + lr;
                    st16(X2bB, row, col, f2bf(s));
                    st16(X2aB, row, col, f2bf(rr * Ev[t][r]));
                }
        }
        barrier_lgkm();   // B2

        // ---- P2a: C = (r*E)@Wc^T ----
        f32x4 aC[4];
        #pragma unroll
        for (int t = 0; t < 4; ++t) aC[t] = f32x4{0.f, 0.f, 0.f, 0.f};
        ldAF(af, X2aB, 0); mm2(aC, af, bufA, 0); issue2(bufA, P2p, 4 * wv, 1, 0);
        ldAF(af, X2aB, 1); mm2(aC, af, bufB, 0); issue2(bufB, P2p, 4 * wv, 1, 1);
        ldAF(af, X2aB, 0); mm2(aC, af, bufA, 1); issue2(bufA, P2p, 16 + 4 * wv, 0, 0);
        ldAF(af, X2aB, 1); mm2(aC, af, bufB, 1); issue2(bufB, P2p, 16 + 4 * wv, 0, 1);

        // ---- P2b: T1 = tanh(S1)@Wz^T ----
        f32x4 aT[4];
        #pragma unroll
        for (int t = 0; t < 4; ++t) aT[t] = f32x4{0.f, 0.f, 0.f, 0.f};
        ldAF(af, X2bB, 0); mm2(aT, af, bufA, 0); issue2(bufA, P2p, 16 + 4 * wv, 1, 0);
        ldAF(af, X2bB, 1); mm2(aT, af, bufB, 0); issue2(bufB, P2p, 16 + 4 * wv, 1, 1);
        ldAF(af, X2bB, 0); mm2(aT, af, bufA, 1); issue2(bufA, P3p, 4 * wv, 0, 0);
        ldAF(af, X2bB, 1); mm2(aT, af, bufB, 1); issue2(bufB, P3p, 4 * wv, 0, 1);

        // epilogue-2: dh_temp -> X3 (aliases X1)
        {
            float tm[4];
            #pragma unroll
            for (int t = 0; t < 4; ++t) tm[t] = ftanh(te * wtv[t]);
            float Ev[4][4]; calcE(Ev, RK);
            #pragma unroll
            for (int t = 0; t < 4; ++t)
                #pragma unroll
                for (int r = 0; r < 4; ++r) {
                    float ht = ftanh(aC[t][r] + bc[t]) + tm[t];
                    float dh = (1.0f - zreg[t][r]) * (ht - Ev[t][r]);
                    st16(X1B, 4 * lg + r, 64 * wv + 16 * t + lr, f2bf(dh));
                }
        }
        barrier_lgkm();   // B3

        // ---- P3: F = dh_temp@Wf1^T ----
        f32x4 aF[4];
        #pragma unroll
        for (int t = 0; t < 4; ++t) aF[t] = f32x4{0.f, 0.f, 0.f, 0.f};
        ldAF(af, X1B, 0); mm2(aF, af, bufA, 0); issue2(bufA, P3p, 4 * wv, 1, 0);
        ldAF(af, X1B, 1); mm2(aF, af, bufB, 0); issue2(bufB, P3p, 4 * wv, 1, 1);
        ldAF(af, X1B, 0); mm2(aF, af, bufA, 1);
        ldAF(af, X1B, 1); mm2(aF, af, bufB, 1);
        barrier_lgkm();   // B4: X1 reads done before next staging

        // P3 epilogue: kv + RK fold (rounding order identical to reference)
        if (RK == 1) {
            #pragma unroll
            for (int t = 0; t < 4; ++t)
                #pragma unroll
                for (int r = 0; r < 4; ++r)
                    kA[t][r] = ftanh(aF[t][r] + aT[t][r] + bfv[t]);
        } else if (RK == 2) {
            #pragma unroll
            for (int t = 0; t < 4; ++t)
                #pragma unroll
                for (int r = 0; r < 4; ++r)
                    kB[t][r] = ftanh(aF[t][r] + aT[t][r] + bfv[t]);
        } else if (RK == 3) {
            #pragma unroll
            for (int t = 0; t < 4; ++t)
                #pragma unroll
                for (int r = 0; r < 4; ++r) {
                    float v = ftanh(aF[t][r] + aT[t][r] + bfv[t]);
                    float a = kA[t][r], b = kB[t][r];
                    kA[t][r] = a + 3.0f * (b + v);   // k1 + 3*(k2+k3)
                    kB[t][r] = (a - b) + v;          // (k1-k2)+k3
                }
        } else {
            #pragma unroll
            for (int t = 0; t < 4; ++t)
                #pragma unroll
                for (int r = 0; r < 4; ++r) {
                    float v = ftanh(aF[t][r] + aT[t][r] + bfv[t]);
                    y[t][r] += dt * 0.125f * (kA[t][r] + v);
                }
        }
    };

    for (int b = 0; b < BATCH; ++b) {
        float t0 = tspans[2 * b], t1 = tspans[2 * b + 1];
        dt = (t1 - t0) / 10.0f;
        for (int s = 0; s < NSTEPS; ++s) {
            float tb = t0 + (float)s * dt;
            EVAL(tb, 1);
            EVAL(tb + dt * third, 2);
            EVAL(tb + dt * 2.0f * third, 3);
            EVAL(tb + dt, 4);
        }
        #pragma unroll
        for (int t = 0; t < 4; ++t)
            #pragma unroll
            for (int r = 0; r < 4; ++r) {
                int row = wg * MTILE + 4 * lg + r;
                int col = 64 * wv + 16 * t + lr;
                out[(b * NROWS + row) * 256 + col] = y[t][r];
            }
    }
}

extern "C" void kernel_launch(void* const* d_in, const int* in_sizes, int n_in,
                              void* d_out, int out_size, void* d_ws, size_t ws_size,
                              hipStream_t stream) {
    (void)in_sizes; (void)n_in; (void)out_size; (void)ws_size;
    const float* h0    = (const float*)d_in[0];
    const float* ts    = (const float*)d_in[1];
    // d_in[2] = adj_matrices : unused (spectral_reg is None)
    const float* Wg_w  = (const float*)d_in[3];
    const float* Wg_b  = (const float*)d_in[4];
    const float* Wc_w  = (const float*)d_in[5];
    const float* Wc_b  = (const float*)d_in[6];
    const float* Wt_w  = (const float*)d_in[7];
    const float* Ws1_w = (const float*)d_in[8];
    const float* Ws1_b = (const float*)d_in[9];
    const float* Ws2_w = (const float*)d_in[10];
    const float* Ws2_b = (const float*)d_in[11];
    const float* Wf_w  = (const float*)d_in[12];
    const float* Wf_b  = (const float*)d_in[13];

    char* ws = (char*)d_ws;
    u16*   P1    = (u16*)(ws);              // 393216 B
    u16*   P2    = (u16*)(ws + 393216);     // 262144 B
    u16*   P3    = (u16*)(ws + 655360);     // 131072 B
    float* Wz    = (float*)(ws + 786432);   // 262144 B
    float* biasf = (float*)(ws + 1048576);  //   1024 B

    hipLaunchKernelGGL(stode_wz,    dim3(256),  dim3(256), 0, stream, Wf_w, Ws2_w, Wz);
    hipLaunchKernelGGL(stode_biasf, dim3(1),    dim3(256), 0, stream, Wf_w, Ws2_b, Wf_b, biasf);
    hipLaunchKernelGGL(stode_pack,  dim3(1536), dim3(256), 0, stream, Wg_w, Ws1_w, Wc_w, Wz, Wf_w, P1, P2, P3);
    hipLaunchKernelGGL(stode_main,  dim3(NWGS), dim3(THREADS), 0, stream,
                       h0, ts, Wg_b, Wc_b, Wt_w, Ws1_b, P1, P2, P3, biasf, (float*)d_out);
}

// Round 4
// 4917.974 us; speedup vs baseline: 2.3999x; 2.3999x over previous
//
#include <hip/hip_runtime.h>
#include <stdint.h>

typedef unsigned short u16;
typedef unsigned int   u32;

typedef short bf16x8 __attribute__((ext_vector_type(8)));   // 8 bf16 in 4 VGPRs
typedef float f32x4  __attribute__((ext_vector_type(4)));

#define NROWS  2048
#define HID    256
#define BATCH  8
#define NSTEPS 10
#define MTILE  16            // rows per workgroup
#define NWGS   (NROWS/MTILE) // 128
#define THREADS 1024         // 16 waves = 4 waves/SIMD @ <=128 VGPR (512 regs/SIMD full)

// ---------- helpers ----------
__device__ __forceinline__ u16 f2bf(float f) {
    union { float f; u32 u; } v; v.f = f;
    u32 r = (v.u + 0x7FFFu + ((v.u >> 16) & 1u)) >> 16;   // RNE
    return (u16)r;
}
__device__ __forceinline__ float sigm(float x) {
    return 1.0f / (1.0f + __expf(-x));
}
__device__ __forceinline__ float ftanh(float x) {
    x = fminf(fmaxf(x, -15.0f), 15.0f);
    float a = __expf(2.0f * x);
    return (a - 1.0f) / (a + 1.0f);
}
__device__ __forceinline__ f32x4 mfma16(bf16x8 a, bf16x8 b, f32x4 c) {
    return __builtin_amdgcn_mfma_f32_16x16x32_bf16(a, b, c, 0, 0, 0);
}
// packed weight B-fragment load: contiguous 16B per lane, 1KB per wave-load
__device__ __forceinline__ bf16x8 loadB(const u16* __restrict__ base, int ct, int kt, int ln) {
    return ((const bf16x8*)base)[(ct * 8 + kt) * 64 + ln];
}
// barrier that does NOT drain vmcnt: LDS visibility via lgkmcnt(0) only.
__device__ __forceinline__ void barrier_lgkm() {
    asm volatile("s_waitcnt lgkmcnt(0)" ::: "memory");
    __builtin_amdgcn_s_barrier();
    asm volatile("" ::: "memory");
}

// ---------- setup kernels (unchanged, validated) ----------
__global__ __launch_bounds__(256) void stode_wz(const float* __restrict__ Wf,
                                                const float* __restrict__ Ws2,
                                                float* __restrict__ Wz) {
    int a = blockIdx.x;
    int b = threadIdx.x;
    const float* wf2 = Wf + a * 512 + 256;
    float acc = 0.0f;
    for (int c = 0; c < 256; ++c) acc += wf2[c] * Ws2[c * 256 + b];
    Wz[a * 256 + b] = acc;
}
__global__ __launch_bounds__(256) void stode_biasf(const float* __restrict__ Wf,
                                                   const float* __restrict__ Ws2b,
                                                   const float* __restrict__ Wfb,
                                                   float* __restrict__ biasf) {
    int a = threadIdx.x;
    const float* wf2 = Wf + a * 512 + 256;
    float acc = Wfb[a];
    for (int c = 0; c < 256; ++c) acc += wf2[c] * Ws2b[c];
    biasf[a] = acc;
}
__global__ __launch_bounds__(256) void stode_pack(const float* __restrict__ Wg,
                                                  const float* __restrict__ Ws1,
                                                  const float* __restrict__ Wc,
                                                  const float* __restrict__ Wz,
                                                  const float* __restrict__ Wf,
                                                  u16* __restrict__ P1,
                                                  u16* __restrict__ P2,
                                                  u16* __restrict__ P3) {
    int i = blockIdx.x * 256 + threadIdx.x;
    const int NP1 = 48 * 8 * 64 * 8;
    const int NP2 = 32 * 8 * 64 * 8;
    int region, local;
    if (i < NP1)            { region = 0; local = i; }
    else if (i < NP1 + NP2) { region = 1; local = i - NP1; }
    else                    { region = 2; local = i - NP1 - NP2; }
    int j    = local & 7;
    int lane = (local >> 3) & 63;
    int kt   = (local >> 9) & 7;
    int ct   = local >> 12;
    int k = kt * 32 + (lane >> 4) * 8 + j;
    int c = lane & 15;
    if (region == 0) {
        float v = (ct < 32) ? Wg[(16 * ct + c) * 256 + k]
                            : Ws1[(16 * (ct - 32) + c) * 256 + k];
        P1[local] = f2bf(v);
    } else if (region == 1) {
        float v = (ct < 16) ? Wc[(16 * ct + c) * 256 + k]
                            : Wz[(16 * (ct - 16) + c) * 256 + k];
        P2[local] = f2bf(v);
    } else {
        float v = Wf[(16 * ct + c) * 512 + k];
        P3[local] = f2bf(v);
    }
}

// ---------- main persistent integrator ----------
// LDS (bytes): X1/X3 alias @0 (8K), X2a @8192 (8K), X2b @16384 (8K), R @24576 (128K) = 155648
#define X1B   0
#define X2aB  8192
#define X2bB  16384
#define WLB   24576

__global__ __launch_bounds__(THREADS) void stode_main(
    const float* __restrict__ h0, const float* __restrict__ tspans,
    const float* __restrict__ Wg_b, const float* __restrict__ Wc_b,
    const float* __restrict__ Wt,   const float* __restrict__ Ws1_b,
    const u16* __restrict__ P1p, const u16* __restrict__ P2p, const u16* __restrict__ P3p,
    const float* __restrict__ biasf, float* __restrict__ out)
{
    __shared__ u16 SH[77824];   // 155648 bytes
    char* shb = (char*)SH;

    const int tid = threadIdx.x;
    const int wv  = tid >> 6;    // 0..15 : wave owns ct = wv (cols 16*wv..16*wv+15)
    const int ln  = tid & 63;
    const int lr  = ln & 15;
    const int lg  = ln >> 4;
    const int wg  = blockIdx.x;
    const float third = 1.0f / 3.0f;

    // A-frag read bases: addr(k) = (k even ? tbE : tbO) + xb + k*64 (reproduces XOR swizzle)
    const int base0 = lr * 512 + ((lg * 16) ^ ((lr & 3) << 4));
    const int flp   = (lr & 4) ? 64 : 0;
    const int tbE   = base0 + flp;
    const int tbO   = base0 - flp;
    const int rBase = WLB + (wv << 13) + (ln << 4);   // LDS-resident R base (8KB/wave)

    auto ldAF = [&](bf16x8 (&af)[4], int xb, int ktH) {
        #pragma unroll
        for (int kk = 0; kk < 4; ++kk) {
            int k = 4 * ktH + kk;
            af[kk] = *(const bf16x8*)(shb + ((k & 1) ? tbO : tbE) + xb + k * 64);
        }
    };
    auto st16 = [&](int xb, int row, int col, u16 v) {
        int byte = (xb + row * 512 + col * 2) ^ ((row & 7) << 4);
        *(u16*)(shb + byte) = v;
    };
    // issue a 4-frag weight chunk (half of one matmul's B operand for this wave)
    auto issue4 = [&](bf16x8 (&buf)[4], const u16* __restrict__ P, int ct, int ktH) {
        #pragma unroll
        for (int kk = 0; kk < 4; ++kk)
            buf[kk] = loadB(P, ct, 4 * ktH + kk, ln);
    };
    auto mm4 = [&](f32x4& acc, const bf16x8 (&af)[4], const bf16x8 (&buf)[4]) {
        #pragma unroll
        for (int kk = 0; kk < 4; ++kk)
            acc = mfma16(af[kk], buf[kk], acc);
    };
    auto ldsRf = [&](int kt) -> bf16x8 {
        return *(const bf16x8*)(shb + rBase + (kt << 10));
    };

    // ---- one-time residency ----
    bf16x8 zf[8];                       // Z weights: 8 frags = 32 persistent VGPRs
    #pragma unroll
    for (int kt = 0; kt < 8; ++kt)
        zf[kt] = loadB(P1p, wv, kt, ln);
    #pragma unroll
    for (int kt = 0; kt < 8; ++kt) {    // R weights -> LDS (own wave's 8KB)
        bf16x8 f = loadB(P1p, 16 + wv, kt, ln);
        *(bf16x8*)(shb + rBase + (kt << 10)) = f;
    }

    // biases / Wt : col = 16*wv + lr
    const int colb = 16 * wv + lr;
    float bz  = Wg_b[colb];
    float br  = Wg_b[256 + colb];
    float bs1 = Ws1_b[colb];
    float bc  = Wc_b[colb];
    float bfv = biasf[colb];
    float wtv = Wt[colb];

    // state at C/D positions: row = 4*lg + r, col = 16*wv + lr
    float y[4], kA[4], kB[4], zreg[4];
    #pragma unroll
    for (int r = 0; r < 4; ++r)
        y[r] = h0[(wg * MTILE + 4 * lg + r) * 256 + colb];

    __syncthreads();   // residency visible (full drain, once)

    float dt = 0.0f;

    // E recomputation (bit-identical per RK stage)
    auto calcE = [&](float (&Ev)[4], int RK) {
        if (RK == 1) {
            #pragma unroll
            for (int r = 0; r < 4; ++r) Ev[r] = y[r];
        } else if (RK == 2) {
            float c = dt * third;
            #pragma unroll
            for (int r = 0; r < 4; ++r) Ev[r] = y[r] + c * kA[r];
        } else if (RK == 3) {
            #pragma unroll
            for (int r = 0; r < 4; ++r) Ev[r] = y[r] + dt * (kB[r] - third * kA[r]);
        } else {
            #pragma unroll
            for (int r = 0; r < 4; ++r) Ev[r] = y[r] + dt * kB[r];
        }
    };

    auto EVAL = [&](float te, int RK) {
        bf16x8 bufA[4], bufB[4];
        // S stream issued a full phase ahead (consumed at end of P1)
        issue4(bufA, P1p, 32 + wv, 0);
        issue4(bufB, P1p, 32 + wv, 1);

        // stage X1 = bf16(E)
        {
            float Ev[4]; calcE(Ev, RK);
            #pragma unroll
            for (int r = 0; r < 4; ++r)
                st16(X1B, 4 * lg + r, colb, f2bf(Ev[r]));
        }
        barrier_lgkm();   // B1 (weight loads stay in flight)

        // ---- P1: Z (reg-resident), R (LDS-resident), S (streamed) ----
        f32x4 aZ = {0.f, 0.f, 0.f, 0.f};
        f32x4 aR = {0.f, 0.f, 0.f, 0.f};
        f32x4 aS = {0.f, 0.f, 0.f, 0.f};
        bf16x8 af[4];
        #pragma unroll
        for (int ktH = 0; ktH < 2; ++ktH) {
            ldAF(af, X1B, ktH);
            #pragma unroll
            for (int kk = 0; kk < 4; ++kk) aZ = mfma16(af[kk], zf[4 * ktH + kk], aZ);
            #pragma unroll
            for (int kk = 0; kk < 4; ++kk) aR = mfma16(af[kk], ldsRf(4 * ktH + kk), aR);
            if (ktH == 0) { mm4(aS, af, bufA); issue4(bufA, P2p, wv, 0); }       // C half0
            else          { mm4(aS, af, bufB); issue4(bufB, P2p, wv, 1); }       // C half1
        }

        // epilogue-1: z,r in regs; write r*E and tanh(S1) tiles
        {
            float Ev[4]; calcE(Ev, RK);
            #pragma unroll
            for (int r = 0; r < 4; ++r) {
                zreg[r]  = sigm(aZ[r] + bz);
                float rr = sigm(aR[r] + br);
                float s  = ftanh(aS[r] + bs1);
                int row = 4 * lg + r;
                st16(X2bB, row, colb, f2bf(s));
                st16(X2aB, row, colb, f2bf(rr * Ev[r]));
            }
        }
        barrier_lgkm();   // B2

        // ---- P2a: C = (r*E)@Wc^T ----
        f32x4 aC = {0.f, 0.f, 0.f, 0.f};
        ldAF(af, X2aB, 0); mm4(aC, af, bufA); issue4(bufA, P2p, 16 + wv, 0);     // T half0
        ldAF(af, X2aB, 1); mm4(aC, af, bufB); issue4(bufB, P2p, 16 + wv, 1);     // T half1

        // ---- P2b: T1 = tanh(S1)@Wz^T ----
        f32x4 aT = {0.f, 0.f, 0.f, 0.f};
        ldAF(af, X2bB, 0); mm4(aT, af, bufA); issue4(bufA, P3p, wv, 0);          // F half0
        ldAF(af, X2bB, 1); mm4(aT, af, bufB); issue4(bufB, P3p, wv, 1);          // F half1

        // epilogue-2: dh_temp -> X3 (aliases X1)
        {
            float tm = ftanh(te * wtv);
            float Ev[4]; calcE(Ev, RK);
            #pragma unroll
            for (int r = 0; r < 4; ++r) {
                float ht = ftanh(aC[r] + bc) + tm;
                float dh = (1.0f - zreg[r]) * (ht - Ev[r]);
                st16(X1B, 4 * lg + r, colb, f2bf(dh));
            }
        }
        barrier_lgkm();   // B3

        // ---- P3: F = dh_temp@Wf1^T ----
        f32x4 aF = {0.f, 0.f, 0.f, 0.f};
        ldAF(af, X1B, 0); mm4(aF, af, bufA);
        ldAF(af, X1B, 1); mm4(aF, af, bufB);
        barrier_lgkm();   // B4: X1 reads done before next eval stages X1

        // epilogue-3: kv + RK fold (rounding order identical to reference)
        if (RK == 1) {
            #pragma unroll
            for (int r = 0; r < 4; ++r)
                kA[r] = ftanh(aF[r] + aT[r] + bfv);
        } else if (RK == 2) {
            #pragma unroll
            for (int r = 0; r < 4; ++r)
                kB[r] = ftanh(aF[r] + aT[r] + bfv);
        } else if (RK == 3) {
            #pragma unroll
            for (int r = 0; r < 4; ++r) {
                float v = ftanh(aF[r] + aT[r] + bfv);
                float a = kA[r], b = kB[r];
                kA[r] = a + 3.0f * (b + v);   // k1 + 3*(k2+k3)
                kB[r] = (a - b) + v;          // (k1-k2)+k3
            }
        } else {
            #pragma unroll
            for (int r = 0; r < 4; ++r) {
                float v = ftanh(aF[r] + aT[r] + bfv);
                y[r] += dt * 0.125f * (kA[r] + v);
            }
        }
    };

    for (int b = 0; b < BATCH; ++b) {
        float t0 = tspans[2 * b], t1 = tspans[2 * b + 1];
        dt = (t1 - t0) / 10.0f;
        for (int s = 0; s < NSTEPS; ++s) {
            float tb = t0 + (float)s * dt;
            EVAL(tb, 1);
            EVAL(tb + dt * third, 2);
            EVAL(tb + dt * 2.0f * third, 3);
            EVAL(tb + dt, 4);
        }
        #pragma unroll
        for (int r = 0; r < 4; ++r) {
            int row = wg * MTILE + 4 * lg + r;
            out[(b * NROWS + row) * 256 + colb] = y[r];
        }
    }
}

extern "C" void kernel_launch(void* const* d_in, const int* in_sizes, int n_in,
                              void* d_out, int out_size, void* d_ws, size_t ws_size,
                              hipStream_t stream) {
    (void)in_sizes; (void)n_in; (void)out_size; (void)ws_size;
    const float* h0    = (const float*)d_in[0];
    const float* ts    = (const float*)d_in[1];
    // d_in[2] = adj_matrices : unused (spectral_reg is None)
    const float* Wg_w  = (const float*)d_in[3];
    const float* Wg_b  = (const float*)d_in[4];
    const float* Wc_w  = (const float*)d_in[5];
    const float* Wc_b  = (const float*)d_in[6];
    const float* Wt_w  = (const float*)d_in[7];
    const float* Ws1_w = (const float*)d_in[8];
    const float* Ws1_b = (const float*)d_in[9];
    const float* Ws2_w = (const float*)d_in[10];
    const float* Ws2_b = (const float*)d_in[11];
    const float* Wf_w  = (const float*)d_in[12];
    const float* Wf_b  = (const float*)d_in[13];

    char* ws = (char*)d_ws;
    u16*   P1    = (u16*)(ws);              // 393216 B
    u16*   P2    = (u16*)(ws + 393216);     // 262144 B
    u16*   P3    = (u16*)(ws + 655360);     // 131072 B
    float* Wz    = (float*)(ws + 786432);   // 262144 B
    float* biasf = (float*)(ws + 1048576);  //   1024 B

    hipLaunchKernelGGL(stode_wz,    dim3(256),  dim3(256), 0, stream, Wf_w, Ws2_w, Wz);
    hipLaunchKernelGGL(stode_biasf, dim3(1),    dim3(256), 0, stream, Wf_w, Ws2_b, Wf_b, biasf);
    hipLaunchKernelGGL(stode_pack,  dim3(1536), dim3(256), 0, stream, Wg_w, Ws1_w, Wc_w, Wz, Wf_w, P1, P2, P3);
    hipLaunchKernelGGL(stode_main,  dim3(NWGS), dim3(THREADS), 0, stream,
                       h0, ts, Wg_b, Wc_b, Wt_w, Ws1_b, P1, P2, P3, biasf, (float*)d_out);
}

// Round 5
// 4850.550 us; speedup vs baseline: 2.4333x; 1.0139x over previous
//
#include <hip/hip_runtime.h>
#include <stdint.h>

typedef unsigned short u16;
typedef unsigned int   u32;

typedef short bf16x8 __attribute__((ext_vector_type(8)));   // 8 bf16 in 4 VGPRs
typedef float f32x4  __attribute__((ext_vector_type(4)));

#define NROWS  2048
#define HID    256
#define BATCH  8
#define NSTEPS 10
#define MTILE  16            // rows per workgroup
#define NWGS   (NROWS/MTILE) // 128
#define THREADS 1024         // 16 waves = 4 waves/SIMD @ 128 VGPR

// ---------- helpers ----------
__device__ __forceinline__ u16 f2bf(float f) {
    union { float f; u32 u; } v; v.f = f;
    u32 r = (v.u + 0x7FFFu + ((v.u >> 16) & 1u)) >> 16;   // RNE
    return (u16)r;
}
__device__ __forceinline__ float sigm(float x) {
    return 1.0f / (1.0f + __expf(-x));
}
__device__ __forceinline__ float ftanh(float x) {
    x = fminf(fmaxf(x, -15.0f), 15.0f);
    float a = __expf(2.0f * x);
    return (a - 1.0f) / (a + 1.0f);
}
__device__ __forceinline__ f32x4 mfma16(bf16x8 a, bf16x8 b, f32x4 c) {
    return __builtin_amdgcn_mfma_f32_16x16x32_bf16(a, b, c, 0, 0, 0);
}
// packed weight B-fragment load: contiguous 16B per lane, 1KB per wave-load
__device__ __forceinline__ bf16x8 loadB(const u16* __restrict__ base, int ct, int kt, int ln) {
    return ((const bf16x8*)base)[(ct * 8 + kt) * 64 + ln];
}
// barrier that does NOT drain vmcnt: LDS visibility via lgkmcnt(0) only.
__device__ __forceinline__ void barrier_lgkm() {
    asm volatile("s_waitcnt lgkmcnt(0)" ::: "memory");
    __builtin_amdgcn_s_barrier();
    asm volatile("" ::: "memory");
}

// ---------- setup kernels (unchanged, validated) ----------
__global__ __launch_bounds__(256) void stode_wz(const float* __restrict__ Wf,
                                                const float* __restrict__ Ws2,
                                                float* __restrict__ Wz) {
    int a = blockIdx.x;
    int b = threadIdx.x;
    const float* wf2 = Wf + a * 512 + 256;
    float acc = 0.0f;
    for (int c = 0; c < 256; ++c) acc += wf2[c] * Ws2[c * 256 + b];
    Wz[a * 256 + b] = acc;
}
__global__ __launch_bounds__(256) void stode_biasf(const float* __restrict__ Wf,
                                                   const float* __restrict__ Ws2b,
                                                   const float* __restrict__ Wfb,
                                                   float* __restrict__ biasf) {
    int a = threadIdx.x;
    const float* wf2 = Wf + a * 512 + 256;
    float acc = Wfb[a];
    for (int c = 0; c < 256; ++c) acc += wf2[c] * Ws2b[c];
    biasf[a] = acc;
}
__global__ __launch_bounds__(256) void stode_pack(const float* __restrict__ Wg,
                                                  const float* __restrict__ Ws1,
                                                  const float* __restrict__ Wc,
                                                  const float* __restrict__ Wz,
                                                  const float* __restrict__ Wf,
                                                  u16* __restrict__ P1,
                                                  u16* __restrict__ P2,
                                                  u16* __restrict__ P3) {
    int i = blockIdx.x * 256 + threadIdx.x;
    const int NP1 = 48 * 8 * 64 * 8;
    const int NP2 = 32 * 8 * 64 * 8;
    int region, local;
    if (i < NP1)            { region = 0; local = i; }
    else if (i < NP1 + NP2) { region = 1; local = i - NP1; }
    else                    { region = 2; local = i - NP1 - NP2; }
    int j    = local & 7;
    int lane = (local >> 3) & 63;
    int kt   = (local >> 9) & 7;
    int ct   = local >> 12;
    int k = kt * 32 + (lane >> 4) * 8 + j;
    int c = lane & 15;
    if (region == 0) {
        float v = (ct < 32) ? Wg[(16 * ct + c) * 256 + k]
                            : Ws1[(16 * (ct - 32) + c) * 256 + k];
        P1[local] = f2bf(v);
    } else if (region == 1) {
        float v = (ct < 16) ? Wc[(16 * ct + c) * 256 + k]
                            : Wz[(16 * (ct - 16) + c) * 256 + k];
        P2[local] = f2bf(v);
    } else {
        float v = Wf[(16 * ct + c) * 512 + k];
        P3[local] = f2bf(v);
    }
}

// ---------- main persistent integrator ----------
// LDS (bytes): 3 rotating 8KB activation slots @0/@8192/@16384, R-resident @24576 (128K) = 152 KB
#define SLOT0 0
#define SLOT1 8192
#define SLOT2 16384
#define WLB   24576

__global__ __launch_bounds__(THREADS, 4) void stode_main(
    const float* __restrict__ h0, const float* __restrict__ tspans,
    const float* __restrict__ Wg_b, const float* __restrict__ Wc_b,
    const float* __restrict__ Wt,   const float* __restrict__ Ws1_b,
    const u16* __restrict__ P1p, const u16* __restrict__ P2p, const u16* __restrict__ P3p,
    const float* __restrict__ biasf, float* __restrict__ out)
{
    __shared__ u16 SH[77824];   // 155648 bytes
    char* shb = (char*)SH;

    const int tid = threadIdx.x;
    const int wv  = tid >> 6;    // 0..15 : wave owns ct = wv (cols 16*wv..16*wv+15)
    const int ln  = tid & 63;
    const int lr  = ln & 15;
    const int lg  = ln >> 4;
    const int wg  = blockIdx.x;
    const float third = 1.0f / 3.0f;

    // A-frag read bases: addr(k) = (k even ? tbE : tbO) + xb + k*64 (reproduces XOR swizzle)
    const int base0 = lr * 512 + ((lg * 16) ^ ((lr & 3) << 4));
    const int flp   = (lr & 4) ? 64 : 0;
    const int tbE   = base0 + flp;
    const int tbO   = base0 - flp;
    const int rBase = WLB + (wv << 13) + (ln << 4);   // LDS-resident R base (8KB/wave)

    auto ldAF = [&](bf16x8 (&af)[4], int xb, int ktH) {
        #pragma unroll
        for (int kk = 0; kk < 4; ++kk) {
            int k = 4 * ktH + kk;
            af[kk] = *(const bf16x8*)(shb + ((k & 1) ? tbO : tbE) + xb + k * 64);
        }
    };
    auto st16 = [&](int xb, int row, int col, u16 v) {
        int byte = (xb + row * 512 + col * 2) ^ ((row & 7) << 4);
        *(u16*)(shb + byte) = v;
    };
    // issue a 4-frag weight chunk (half of one matmul's B operand for this wave)
    auto issue4 = [&](bf16x8 (&buf)[4], const u16* __restrict__ P, int ct, int ktH) {
        #pragma unroll
        for (int kk = 0; kk < 4; ++kk)
            buf[kk] = loadB(P, ct, 4 * ktH + kk, ln);
    };
    auto mm4 = [&](f32x4& acc, const bf16x8 (&af)[4], const bf16x8 (&buf)[4]) {
        #pragma unroll
        for (int kk = 0; kk < 4; ++kk)
            acc = mfma16(af[kk], buf[kk], acc);
    };
    auto ldsRf = [&](int kt) -> bf16x8 {
        return *(const bf16x8*)(shb + rBase + (kt << 10));
    };

    // ---- one-time residency ----
    bf16x8 zfH[4];                      // Z weights kt 0..3 resident (16 VGPRs); kt 4..7 streamed
    #pragma unroll
    for (int kt = 0; kt < 4; ++kt)
        zfH[kt] = loadB(P1p, wv, kt, ln);
    #pragma unroll
    for (int kt = 0; kt < 8; ++kt) {    // R weights -> LDS (own wave's 8KB)
        bf16x8 f = loadB(P1p, 16 + wv, kt, ln);
        *(bf16x8*)(shb + rBase + (kt << 10)) = f;
    }

    // biases / Wt : col = 16*wv + lr
    const int colb = 16 * wv + lr;
    float bz  = Wg_b[colb];
    float br  = Wg_b[256 + colb];
    float bs1 = Ws1_b[colb];
    float bc  = Wc_b[colb];
    float bfv = biasf[colb];
    float wtv = Wt[colb];

    // state at C/D positions: row = 4*lg + r, col = 16*wv + lr
    float y[4], kA[4], kB[4], zreg[4];
    #pragma unroll
    for (int r = 0; r < 4; ++r)
        y[r] = h0[(wg * MTILE + 4 * lg + r) * 256 + colb];

    __syncthreads();   // residency visible (full drain, once)

    float dt = 0.0f;

    // E recomputation (bit-identical per RK stage)
    auto calcE = [&](float (&Ev)[4], int RK) {
        if (RK == 1) {
            #pragma unroll
            for (int r = 0; r < 4; ++r) Ev[r] = y[r];
        } else if (RK == 2) {
            float c = dt * third;
            #pragma unroll
            for (int r = 0; r < 4; ++r) Ev[r] = y[r] + c * kA[r];
        } else if (RK == 3) {
            #pragma unroll
            for (int r = 0; r < 4; ++r) Ev[r] = y[r] + dt * (kB[r] - third * kA[r]);
        } else {
            #pragma unroll
            for (int r = 0; r < 4; ++r) Ev[r] = y[r] + dt * kB[r];
        }
    };

    // rotating activation slots + 3 stream buffers
    int bE = SLOT0, bRE = SLOT1, bTS = SLOT2;
    bf16x8 b0[4], b1[4], b2[4];

    // prologue: first eval's in-flight chunks: S0->b0, Z1->b1, S1->b2
    issue4(b0, P1p, 32 + wv, 0);
    issue4(b1, P1p,      wv, 1);
    issue4(b2, P1p, 32 + wv, 1);

    auto EVAL = [&](float te, int RK) {
        // stage X_E = bf16(E)
        {
            float Ev[4]; calcE(Ev, RK);
            #pragma unroll
            for (int r = 0; r < 4; ++r)
                st16(bE, 4 * lg + r, colb, f2bf(Ev[r]));
        }
        barrier_lgkm();   // B1 (weight loads stay in flight)

        // ---- P1: Z (half-resident + streamed), R (LDS-resident), S (streamed) ----
        f32x4 aZ = {0.f, 0.f, 0.f, 0.f};
        f32x4 aR = {0.f, 0.f, 0.f, 0.f};
        f32x4 aS = {0.f, 0.f, 0.f, 0.f};
        bf16x8 af[4];
        // ktH0
        ldAF(af, bE, 0);
        #pragma unroll
        for (int kk = 0; kk < 4; ++kk) aZ = mfma16(af[kk], zfH[kk], aZ);
        #pragma unroll
        for (int kk = 0; kk < 4; ++kk) aR = mfma16(af[kk], ldsRf(kk), aR);
        mm4(aS, af, b0);                          // consume S0
        issue4(b0, P2p, wv, 0);                   // issue  C0
        // ktH1
        ldAF(af, bE, 1);
        mm4(aZ, af, b1);                          // consume Z1 (streamed kt4..7)
        #pragma unroll
        for (int kk = 0; kk < 4; ++kk) aR = mfma16(af[kk], ldsRf(4 + kk), aR);
        mm4(aS, af, b2);                          // consume S1
        issue4(b1, P2p, wv, 1);                   // issue  C1
        issue4(b2, P2p, 16 + wv, 0);              // issue  T0

        // epilogue-1: z,r in regs; write r*E and tanh(S1) tiles
        {
            float Ev[4]; calcE(Ev, RK);
            #pragma unroll
            for (int r = 0; r < 4; ++r) {
                zreg[r]  = sigm(aZ[r] + bz);
                float rr = sigm(aR[r] + br);
                float s  = ftanh(aS[r] + bs1);
                int row = 4 * lg + r;
                st16(bTS, row, colb, f2bf(s));
                st16(bRE, row, colb, f2bf(rr * Ev[r]));
            }
        }
        barrier_lgkm();   // B2

        // ---- P2a: C = (r*E)@Wc^T ----
        f32x4 aC = {0.f, 0.f, 0.f, 0.f};
        ldAF(af, bRE, 0); mm4(aC, af, b0); issue4(b0, P2p, 16 + wv, 1);   // C0 -> T1
        ldAF(af, bRE, 1); mm4(aC, af, b1); issue4(b1, P3p, wv, 0);        // C1 -> F0

        // ---- P2b: T1 = tanh(S1)@Wz^T ----
        f32x4 aT = {0.f, 0.f, 0.f, 0.f};
        ldAF(af, bTS, 0); mm4(aT, af, b2); issue4(b2, P3p, wv, 1);        // T0 -> F1
        ldAF(af, bTS, 1); mm4(aT, af, b0); issue4(b0, P1p, 32 + wv, 0);   // T1 -> S0'

        // epilogue-2: dh_temp -> X_E slot (safe: all waves passed B2, P1 reads done)
        {
            float tm = ftanh(te * wtv);
            float Ev[4]; calcE(Ev, RK);
            #pragma unroll
            for (int r = 0; r < 4; ++r) {
                float ht = ftanh(aC[r] + bc) + tm;
                float dh = (1.0f - zreg[r]) * (ht - Ev[r]);
                st16(bE, 4 * lg + r, colb, f2bf(dh));
            }
        }
        barrier_lgkm();   // B3

        // ---- P3: F = dh_temp@Wf1^T ----
        f32x4 aF = {0.f, 0.f, 0.f, 0.f};
        ldAF(af, bE, 0); mm4(aF, af, b1); issue4(b1, P1p, wv, 1);         // F0 -> Z1'
        ldAF(af, bE, 1); mm4(aF, af, b2); issue4(b2, P1p, 32 + wv, 1);    // F1 -> S1'

        // epilogue-3: kv + RK fold (rounding order identical to reference)
        if (RK == 1) {
            #pragma unroll
            for (int r = 0; r < 4; ++r)
                kA[r] = ftanh(aF[r] + aT[r] + bfv);
        } else if (RK == 2) {
            #pragma unroll
            for (int r = 0; r < 4; ++r)
                kB[r] = ftanh(aF[r] + aT[r] + bfv);
        } else if (RK == 3) {
            #pragma unroll
            for (int r = 0; r < 4; ++r) {
                float v = ftanh(aF[r] + aT[r] + bfv);
                float a = kA[r], b = kB[r];
                kA[r] = a + 3.0f * (b + v);   // k1 + 3*(k2+k3)
                kB[r] = (a - b) + v;          // (k1-k2)+k3
            }
        } else {
            #pragma unroll
            for (int r = 0; r < 4; ++r) {
                float v = ftanh(aF[r] + aT[r] + bfv);
                y[r] += dt * 0.125f * (kA[r] + v);
            }
        }

        // rotate activation slots: next E -> old rE slot (WAR-safe)
        int tmp = bE; bE = bRE; bRE = bTS; bTS = tmp;
    };

    for (int b = 0; b < BATCH; ++b) {
        float t0 = tspans[2 * b], t1 = tspans[2 * b + 1];
        dt = (t1 - t0) / 10.0f;
        for (int s = 0; s < NSTEPS; ++s) {
            float tb = t0 + (float)s * dt;
            EVAL(tb, 1);
            EVAL(tb + dt * third, 2);
            EVAL(tb + dt * 2.0f * third, 3);
            EVAL(tb + dt, 4);
        }
        #pragma unroll
        for (int r = 0; r < 4; ++r) {
            int row = wg * MTILE + 4 * lg + r;
            out[(b * NROWS + row) * 256 + colb] = y[r];
        }
    }
}

extern "C" void kernel_launch(void* const* d_in, const int* in_sizes, int n_in,
                              void* d_out, int out_size, void* d_ws, size_t ws_size,
                              hipStream_t stream) {
    (void)in_sizes; (void)n_in; (void)out_size; (void)ws_size;
    const float* h0    = (const float*)d_in[0];
    const float* ts    = (const float*)d_in[1];
    // d_in[2] = adj_matrices : unused (spectral_reg is None)
    const float* Wg_w  = (const float*)d_in[3];
    const float* Wg_b  = (const float*)d_in[4];
    const float* Wc_w  = (const float*)d_in[5];
    const float* Wc_b  = (const float*)d_in[6];
    const float* Wt_w  = (const float*)d_in[7];
    const float* Ws1_w = (const float*)d_in[8];
    const float* Ws1_b = (const float*)d_in[9];
    const float* Ws2_w = (const float*)d_in[10];
    const float* Ws2_b = (const float*)d_in[11];
    const float* Wf_w  = (const float*)d_in[12];
    const float* Wf_b  = (const float*)d_in[13];

    char* ws = (char*)d_ws;
    u16*   P1    = (u16*)(ws);              // 393216 B
    u16*   P2    = (u16*)(ws + 393216);     // 262144 B
    u16*   P3    = (u16*)(ws + 655360);     // 131072 B
    float* Wz    = (float*)(ws + 786432);   // 262144 B
    float* biasf = (float*)(ws + 1048576);  //   1024 B

    hipLaunchKernelGGL(stode_wz,    dim3(256),  dim3(256), 0, stream, Wf_w, Ws2_w, Wz);
    hipLaunchKernelGGL(stode_biasf, dim3(1),    dim3(256), 0, stream, Wf_w, Ws2_b, Wf_b, biasf);
    hipLaunchKernelGGL(stode_pack,  dim3(1536), dim3(256), 0, stream, Wg_w, Ws1_w, Wc_w, Wz, Wf_w, P1, P2, P3);
    hipLaunchKernelGGL(stode_main,  dim3(NWGS), dim3(THREADS), 0, stream,
                       h0, ts, Wg_b, Wc_b, Wt_w, Ws1_b, P1, P2, P3, biasf, (float*)d_out);
}

// Round 6
// 4843.387 us; speedup vs baseline: 2.4369x; 1.0015x over previous
//
#include <hip/hip_runtime.h>
#include <stdint.h>

typedef unsigned short u16;
typedef unsigned int   u32;

typedef short bf16x8 __attribute__((ext_vector_type(8)));   // 8 bf16 in 4 VGPRs
typedef float f32x4  __attribute__((ext_vector_type(4)));

#define NROWS  2048
#define HID    256
#define BATCH  8
#define NSTEPS 10
#define MTILE  16            // rows per workgroup
#define NWGS   (NROWS/MTILE) // 128
#define THREADS 1024         // 16 waves = 4 waves/SIMD @ 128 VGPR (forced via waves_per_eu(4,4))

// ---------- helpers ----------
__device__ __forceinline__ u16 f2bf(float f) {
    union { float f; u32 u; } v; v.f = f;
    u32 r = (v.u + 0x7FFFu + ((v.u >> 16) & 1u)) >> 16;   // RNE
    return (u16)r;
}
__device__ __forceinline__ float sigm(float x) {
    return 1.0f / (1.0f + __expf(-x));
}
__device__ __forceinline__ float ftanh(float x) {
    x = fminf(fmaxf(x, -15.0f), 15.0f);
    float a = __expf(2.0f * x);
    return (a - 1.0f) / (a + 1.0f);
}
__device__ __forceinline__ f32x4 mfma16(bf16x8 a, bf16x8 b, f32x4 c) {
    return __builtin_amdgcn_mfma_f32_16x16x32_bf16(a, b, c, 0, 0, 0);
}
// packed weight B-fragment load: contiguous 16B per lane, 1KB per wave-load
__device__ __forceinline__ bf16x8 loadB(const u16* __restrict__ base, int ct, int kt, int ln) {
    return ((const bf16x8*)base)[(ct * 8 + kt) * 64 + ln];
}
// barrier that does NOT drain vmcnt: LDS visibility via lgkmcnt(0) only.
__device__ __forceinline__ void barrier_lgkm() {
    asm volatile("s_waitcnt lgkmcnt(0)" ::: "memory");
    __builtin_amdgcn_s_barrier();
    asm volatile("" ::: "memory");
}

// ---------- setup kernels (unchanged, validated) ----------
__global__ __launch_bounds__(256) void stode_wz(const float* __restrict__ Wf,
                                                const float* __restrict__ Ws2,
                                                float* __restrict__ Wz) {
    int a = blockIdx.x;
    int b = threadIdx.x;
    const float* wf2 = Wf + a * 512 + 256;
    float acc = 0.0f;
    for (int c = 0; c < 256; ++c) acc += wf2[c] * Ws2[c * 256 + b];
    Wz[a * 256 + b] = acc;
}
__global__ __launch_bounds__(256) void stode_biasf(const float* __restrict__ Wf,
                                                   const float* __restrict__ Ws2b,
                                                   const float* __restrict__ Wfb,
                                                   float* __restrict__ biasf) {
    int a = threadIdx.x;
    const float* wf2 = Wf + a * 512 + 256;
    float acc = Wfb[a];
    for (int c = 0; c < 256; ++c) acc += wf2[c] * Ws2b[c];
    biasf[a] = acc;
}
__global__ __launch_bounds__(256) void stode_pack(const float* __restrict__ Wg,
                                                  const float* __restrict__ Ws1,
                                                  const float* __restrict__ Wc,
                                                  const float* __restrict__ Wz,
                                                  const float* __restrict__ Wf,
                                                  u16* __restrict__ P1,
                                                  u16* __restrict__ P2,
                                                  u16* __restrict__ P3) {
    int i = blockIdx.x * 256 + threadIdx.x;
    const int NP1 = 48 * 8 * 64 * 8;
    const int NP2 = 32 * 8 * 64 * 8;
    int region, local;
    if (i < NP1)            { region = 0; local = i; }
    else if (i < NP1 + NP2) { region = 1; local = i - NP1; }
    else                    { region = 2; local = i - NP1 - NP2; }
    int j    = local & 7;
    int lane = (local >> 3) & 63;
    int kt   = (local >> 9) & 7;
    int ct   = local >> 12;
    int k = kt * 32 + (lane >> 4) * 8 + j;
    int c = lane & 15;
    if (region == 0) {
        float v = (ct < 32) ? Wg[(16 * ct + c) * 256 + k]
                            : Ws1[(16 * (ct - 32) + c) * 256 + k];
        P1[local] = f2bf(v);
    } else if (region == 1) {
        float v = (ct < 16) ? Wc[(16 * ct + c) * 256 + k]
                            : Wz[(16 * (ct - 16) + c) * 256 + k];
        P2[local] = f2bf(v);
    } else {
        float v = Wf[(16 * ct + c) * 512 + k];
        P3[local] = f2bf(v);
    }
}

// ---------- main persistent integrator ----------
// LDS (bytes): 3 rotating 8KB activation slots @0/@8192/@16384, R-resident @24576 (128K) = 152 KB
#define SLOT0 0
#define SLOT1 8192
#define SLOT2 16384
#define WLB   24576

__global__ void __launch_bounds__(THREADS)
__attribute__((amdgpu_waves_per_eu(4, 4)))   // pin 4 waves/EU: VGPR budget = 128, no 64-reg squeeze
stode_main(
    const float* __restrict__ h0, const float* __restrict__ tspans,
    const float* __restrict__ Wg_b, const float* __restrict__ Wc_b,
    const float* __restrict__ Wt,   const float* __restrict__ Ws1_b,
    const u16* __restrict__ P1p, const u16* __restrict__ P2p, const u16* __restrict__ P3p,
    const float* __restrict__ biasf, float* __restrict__ out)
{
    __shared__ u16 SH[77824];   // 155648 bytes
    char* shb = (char*)SH;

    const int tid = threadIdx.x;
    const int wv  = tid >> 6;    // 0..15 : wave owns ct = wv (cols 16*wv..16*wv+15)
    const int ln  = tid & 63;
    const int lr  = ln & 15;
    const int lg  = ln >> 4;
    const int wg  = blockIdx.x;
    const float third = 1.0f / 3.0f;

    // A-frag read bases: addr(k) = (k even ? tbE : tbO) + xb + k*64 (reproduces XOR swizzle)
    const int base0 = lr * 512 + ((lg * 16) ^ ((lr & 3) << 4));
    const int flp   = (lr & 4) ? 64 : 0;
    const int tbE   = base0 + flp;
    const int tbO   = base0 - flp;
    const int rBase = WLB + (wv << 13) + (ln << 4);   // LDS-resident R base (8KB/wave)

    auto ldAF = [&](bf16x8 (&af)[4], int xb, int ktH) {
        #pragma unroll
        for (int kk = 0; kk < 4; ++kk) {
            int k = 4 * ktH + kk;
            af[kk] = *(const bf16x8*)(shb + ((k & 1) ? tbO : tbE) + xb + k * 64);
        }
    };
    auto st16 = [&](int xb, int row, int col, u16 v) {
        int byte = (xb + row * 512 + col * 2) ^ ((row & 7) << 4);
        *(u16*)(shb + byte) = v;
    };
    // issue a 4-frag weight chunk (half of one matmul's B operand for this wave)
    auto issue4 = [&](bf16x8 (&buf)[4], const u16* __restrict__ P, int ct, int ktH) {
        #pragma unroll
        for (int kk = 0; kk < 4; ++kk)
            buf[kk] = loadB(P, ct, 4 * ktH + kk, ln);
    };
    auto mm4 = [&](f32x4& acc, const bf16x8 (&af)[4], const bf16x8 (&buf)[4]) {
        #pragma unroll
        for (int kk = 0; kk < 4; ++kk)
            acc = mfma16(af[kk], buf[kk], acc);
    };
    auto ldsRf = [&](int kt) -> bf16x8 {
        return *(const bf16x8*)(shb + rBase + (kt << 10));
    };

    // ---- one-time residency ----
    bf16x8 zfH[4];                      // Z weights kt 0..3 resident (16 VGPRs); kt 4..7 streamed
    #pragma unroll
    for (int kt = 0; kt < 4; ++kt)
        zfH[kt] = loadB(P1p, wv, kt, ln);
    #pragma unroll
    for (int kt = 0; kt < 8; ++kt) {    // R weights -> LDS (own wave's 8KB)
        bf16x8 f = loadB(P1p, 16 + wv, kt, ln);
        *(bf16x8*)(shb + rBase + (kt << 10)) = f;
    }

    // biases / Wt : col = 16*wv + lr
    const int colb = 16 * wv + lr;
    float bz  = Wg_b[colb];
    float br  = Wg_b[256 + colb];
    float bs1 = Ws1_b[colb];
    float bc  = Wc_b[colb];
    float bfv = biasf[colb];
    float wtv = Wt[colb];

    // state at C/D positions: row = 4*lg + r, col = 16*wv + lr
    float y[4], kA[4], kB[4], zreg[4];
    #pragma unroll
    for (int r = 0; r < 4; ++r)
        y[r] = h0[(wg * MTILE + 4 * lg + r) * 256 + colb];

    __syncthreads();   // residency visible (full drain, once)

    float dt = 0.0f;

    // E recomputation (bit-identical per RK stage)
    auto calcE = [&](float (&Ev)[4], int RK) {
        if (RK == 1) {
            #pragma unroll
            for (int r = 0; r < 4; ++r) Ev[r] = y[r];
        } else if (RK == 2) {
            float c = dt * third;
            #pragma unroll
            for (int r = 0; r < 4; ++r) Ev[r] = y[r] + c * kA[r];
        } else if (RK == 3) {
            #pragma unroll
            for (int r = 0; r < 4; ++r) Ev[r] = y[r] + dt * (kB[r] - third * kA[r]);
        } else {
            #pragma unroll
            for (int r = 0; r < 4; ++r) Ev[r] = y[r] + dt * kB[r];
        }
    };

    // rotating activation slots + 3 stream buffers
    int bE = SLOT0, bRE = SLOT1, bTS = SLOT2;
    bf16x8 b0[4], b1[4], b2[4];

    // prologue: first eval's in-flight chunks: S0->b0, Z1->b1, S1->b2
    issue4(b0, P1p, 32 + wv, 0);
    issue4(b1, P1p,      wv, 1);
    issue4(b2, P1p, 32 + wv, 1);

    auto EVAL = [&](float te, int RK) {
        // stage X_E = bf16(E)
        {
            float Ev[4]; calcE(Ev, RK);
            #pragma unroll
            for (int r = 0; r < 4; ++r)
                st16(bE, 4 * lg + r, colb, f2bf(Ev[r]));
        }
        barrier_lgkm();   // B1 (weight loads stay in flight)

        // ---- P1: Z (half-resident + streamed), R (LDS-resident), S (streamed) ----
        f32x4 aZ = {0.f, 0.f, 0.f, 0.f};
        f32x4 aR = {0.f, 0.f, 0.f, 0.f};
        f32x4 aS = {0.f, 0.f, 0.f, 0.f};
        bf16x8 af[4];
        // ktH0
        ldAF(af, bE, 0);
        #pragma unroll
        for (int kk = 0; kk < 4; ++kk) aZ = mfma16(af[kk], zfH[kk], aZ);
        #pragma unroll
        for (int kk = 0; kk < 4; ++kk) aR = mfma16(af[kk], ldsRf(kk), aR);
        mm4(aS, af, b0);                          // consume S0
        issue4(b0, P2p, wv, 0);                   // issue  C0
        // ktH1
        ldAF(af, bE, 1);
        mm4(aZ, af, b1);                          // consume Z1 (streamed kt4..7)
        #pragma unroll
        for (int kk = 0; kk < 4; ++kk) aR = mfma16(af[kk], ldsRf(4 + kk), aR);
        mm4(aS, af, b2);                          // consume S1
        issue4(b1, P2p, wv, 1);                   // issue  C1
        issue4(b2, P2p, 16 + wv, 0);              // issue  T0

        // epilogue-1: z,r in regs; write r*E and tanh(S1) tiles
        {
            float Ev[4]; calcE(Ev, RK);
            #pragma unroll
            for (int r = 0; r < 4; ++r) {
                zreg[r]  = sigm(aZ[r] + bz);
                float rr = sigm(aR[r] + br);
                float s  = ftanh(aS[r] + bs1);
                int row = 4 * lg + r;
                st16(bTS, row, colb, f2bf(s));
                st16(bRE, row, colb, f2bf(rr * Ev[r]));
            }
        }
        barrier_lgkm();   // B2

        // ---- P2a: C = (r*E)@Wc^T ----
        f32x4 aC = {0.f, 0.f, 0.f, 0.f};
        ldAF(af, bRE, 0); mm4(aC, af, b0); issue4(b0, P2p, 16 + wv, 1);   // C0 -> T1
        ldAF(af, bRE, 1); mm4(aC, af, b1); issue4(b1, P3p, wv, 0);        // C1 -> F0

        // ---- P2b: T1 = tanh(S1)@Wz^T ----
        f32x4 aT = {0.f, 0.f, 0.f, 0.f};
        ldAF(af, bTS, 0); mm4(aT, af, b2); issue4(b2, P3p, wv, 1);        // T0 -> F1
        ldAF(af, bTS, 1); mm4(aT, af, b0); issue4(b0, P1p, 32 + wv, 0);   // T1 -> S0'

        // epilogue-2: dh_temp -> X_E slot (safe: all waves passed B2, P1 reads done)
        {
            float tm = ftanh(te * wtv);
            float Ev[4]; calcE(Ev, RK);
            #pragma unroll
            for (int r = 0; r < 4; ++r) {
                float ht = ftanh(aC[r] + bc) + tm;
                float dh = (1.0f - zreg[r]) * (ht - Ev[r]);
                st16(bE, 4 * lg + r, colb, f2bf(dh));
            }
        }
        barrier_lgkm();   // B3

        // ---- P3: F = dh_temp@Wf1^T ----
        f32x4 aF = {0.f, 0.f, 0.f, 0.f};
        ldAF(af, bE, 0); mm4(aF, af, b1); issue4(b1, P1p, wv, 1);         // F0 -> Z1'
        ldAF(af, bE, 1); mm4(aF, af, b2); issue4(b2, P1p, 32 + wv, 1);    // F1 -> S1'

        // epilogue-3: kv + RK fold (rounding order identical to reference)
        if (RK == 1) {
            #pragma unroll
            for (int r = 0; r < 4; ++r)
                kA[r] = ftanh(aF[r] + aT[r] + bfv);
        } else if (RK == 2) {
            #pragma unroll
            for (int r = 0; r < 4; ++r)
                kB[r] = ftanh(aF[r] + aT[r] + bfv);
        } else if (RK == 3) {
            #pragma unroll
            for (int r = 0; r < 4; ++r) {
                float v = ftanh(aF[r] + aT[r] + bfv);
                float a = kA[r], b = kB[r];
                kA[r] = a + 3.0f * (b + v);   // k1 + 3*(k2+k3)
                kB[r] = (a - b) + v;          // (k1-k2)+k3
            }
        } else {
            #pragma unroll
            for (int r = 0; r < 4; ++r) {
                float v = ftanh(aF[r] + aT[r] + bfv);
                y[r] += dt * 0.125f * (kA[r] + v);
            }
        }

        // rotate activation slots: next E -> old rE slot (WAR-safe)
        int tmp = bE; bE = bRE; bRE = bTS; bTS = tmp;
    };

    for (int b = 0; b < BATCH; ++b) {
        float t0 = tspans[2 * b], t1 = tspans[2 * b + 1];
        dt = (t1 - t0) / 10.0f;
        for (int s = 0; s < NSTEPS; ++s) {
            float tb = t0 + (float)s * dt;
            EVAL(tb, 1);
            EVAL(tb + dt * third, 2);
            EVAL(tb + dt * 2.0f * third, 3);
            EVAL(tb + dt, 4);
        }
        #pragma unroll
        for (int r = 0; r < 4; ++r) {
            int row = wg * MTILE + 4 * lg + r;
            out[(b * NROWS + row) * 256 + colb] = y[r];
        }
    }
}

extern "C" void kernel_launch(void* const* d_in, const int* in_sizes, int n_in,
                              void* d_out, int out_size, void* d_ws, size_t ws_size,
                              hipStream_t stream) {
    (void)in_sizes; (void)n_in; (void)out_size; (void)ws_size;
    const float* h0    = (const float*)d_in[0];
    const float* ts    = (const float*)d_in[1];
    // d_in[2] = adj_matrices : unused (spectral_reg is None)
    const float* Wg_w  = (const float*)d_in[3];
    const float* Wg_b  = (const float*)d_in[4];
    const float* Wc_w  = (const float*)d_in[5];
    const float* Wc_b  = (const float*)d_in[6];
    const float* Wt_w  = (const float*)d_in[7];
    const float* Ws1_w = (const float*)d_in[8];
    const float* Ws1_b = (const float*)d_in[9];
    const float* Ws2_w = (const float*)d_in[10];
    const float* Ws2_b = (const float*)d_in[11];
    const float* Wf_w  = (const float*)d_in[12];
    const float* Wf_b  = (const float*)d_in[13];

    char* ws = (char*)d_ws;
    u16*   P1    = (u16*)(ws);              // 393216 B
    u16*   P2    = (u16*)(ws + 393216);     // 262144 B
    u16*   P3    = (u16*)(ws + 655360);     // 131072 B
    float* Wz    = (float*)(ws + 786432);   // 262144 B
    float* biasf = (float*)(ws + 1048576);  //   1024 B

    hipLaunchKernelGGL(stode_wz,    dim3(256),  dim3(256), 0, stream, Wf_w, Ws2_w, Wz);
    hipLaunchKernelGGL(stode_biasf, dim3(1),    dim3(256), 0, stream, Wf_w, Ws2_b, Wf_b, biasf);
    hipLaunchKernelGGL(stode_pack,  dim3(1536), dim3(256), 0, stream, Wg_w, Ws1_w, Wc_w, Wz, Wf_w, P1, P2, P3);
    hipLaunchKernelGGL(stode_main,  dim3(NWGS), dim3(THREADS), 0, stream,
                       h0, ts, Wg_b, Wc_b, Wt_w, Ws1_b, P1, P2, P3, biasf, (float*)d_out);
}